// Round 5
// baseline (158.467 us; speedup 1.0000x reference)
//
#include <hip/hip_runtime.h>
#include <hip/hip_bf16.h>

#define B 32
#define T 8192
#define H 128

typedef __attribute__((ext_vector_type(8)))  short short8_t;   // 8 bf16 = 4 VGPR
typedef __attribute__((ext_vector_type(16))) float f32x16;     // MFMA 32x32 acc
typedef __attribute__((ext_vector_type(4)))  float f32x4;

static __device__ __forceinline__ unsigned fbits(float x) { return __builtin_bit_cast(unsigned, x); }
static __device__ __forceinline__ float bfloat(unsigned u) { return __builtin_bit_cast(float, u); }

// ws layout: [0,16K) u fp32 ; [16K,48K) W2 hi-frags bf16 ; [48K,80K) W2 lo-frags
#define WPK_OFF 16384

// ---------------------------------------------------------------------------
// Kernel 1 (merged prep): blocks 0..31 -> u[b][h]; blocks 32..39 -> pack W2.
//   u[b][h] = b_attn[h] + dot(W1[h,:], hidden[b,:])          (fp32 exact)
//   wpk: A-frags for v_mfma_f32_32x32x16_bf16, hi plane then lo plane.
//   A-frag: lane l supplies A[m*32 + (l&31)][s*16 + (l>>5)*8 + e], e=0..7;
//   buffer index frag[s][m][lane][e].
// ---------------------------------------------------------------------------
__global__ void k_prep(const float* __restrict__ hidden,
                       const float* __restrict__ W_attn,
                       const float* __restrict__ b_attn,
                       float* __restrict__ u,
                       unsigned short* __restrict__ wpk) {
    const int tid = threadIdx.x;
    if (blockIdx.x < 32) {
        const int b = blockIdx.x;
        __shared__ float hrow[H];
        if (tid < H) hrow[tid] = hidden[b * H + tid];
        __syncthreads();
        if (tid < H) {
            const float* w = W_attn + (size_t)tid * (2 * H);
            float acc = b_attn[tid];
#pragma unroll
            for (int k = 0; k < H; ++k) acc = fmaf(w[k], hrow[k], acc);
            u[b * H + tid] = acc;
        }
    } else {
        const int idx  = (blockIdx.x - 32) * 256 + tid;   // 0..2047
        const int s    = idx >> 8;
        const int m    = (idx >> 6) & 3;
        const int lane = idx & 63;
        const int h    = m * 32 + (lane & 31);
        const int k0   = s * 16 + (lane >> 5) * 8;
        const float* src = W_attn + (size_t)h * (2 * H) + H + k0;
        const int base = ((s * 4 + m) * 64 + lane) * 8;
#pragma unroll
        for (int e = 0; e < 8; ++e) {
            const float x = src[e];
            const unsigned ux = fbits(x);
            const unsigned hb = ux & 0xffff0000u;         // truncated bf16 hi
            const float r = x - bfloat(hb);               // exact remainder
            wpk[base + e]         = (unsigned short)(ux >> 16);
            wpk[16384 + base + e] = (unsigned short)(fbits(r) >> 16);
        }
    }
}

// ---------------------------------------------------------------------------
// Kernel 2: scores via MFMA, wave-paired (mh = h-half), barrier-free gi loop.
// Block = 512 thr = 8 waves = 4 pairs; 16 t-values per block (4 per pair).
// Each wave writes its partial scores into private pbuf slots; ONE barrier;
// then a fused flush sums the pair halves and stores coalesced (16 dwords =
// one 64B line per b). Grid 512 = all blocks co-resident (2 blocks/CU).
// ---------------------------------------------------------------------------
__global__ __launch_bounds__(512, 4) void k_scores_mfma(
    const float* __restrict__ enc,                 // [T*B][H]
    const float* __restrict__ u,                   // [B][H]
    const float* __restrict__ v,                   // [H]
    const unsigned short* __restrict__ wpk,        // 64 KB frag-ordered hi|lo
    float* __restrict__ scores)                    // [B][T]
{
    __shared__ unsigned short wlds[32768];         // 64 KB
    __shared__ float pbuf[2][32][17];              // [mh][b][gcol] padded

    const int tid  = threadIdx.x;
    const int lane = tid & 63;
    const int wid  = tid >> 6;      // 0..7
    const int pair = wid >> 1;      // 0..3 : t-group owner
    const int mh   = wid & 1;       // h-half: tiles {2mh, 2mh+1}
    const int l31  = lane & 31;
    const int kh   = lane >> 5;
    const int mt0  = mh * 2;
    const int mt1  = mh * 2 + 1;

    // one-time stage of packed W2 frags
    {
        const f32x4* src = (const f32x4*)wpk;
        f32x4* dst = (f32x4*)wlds;
#pragma unroll
        for (int i = 0; i < 8; ++i) dst[tid + i * 512] = src[tid + i * 512];
    }
    __syncthreads();

    const int gbase = blockIdx.x * 16;

#pragma unroll 1
    for (int gi = 0; gi < 4; ++gi) {
        const int gcol = pair * 4 + gi;
        const int g    = gbase + gcol;             // t index

        // --- acc init = u fragment (C/D row = j + 8*r4 + 4*kh, col = b = l31)
        f32x16 acc0, acc1;
#pragma unroll
        for (int r4 = 0; r4 < 4; ++r4) {
            const f32x4 t0 = *(const f32x4*)(u + l31 * H + mt0 * 32 + r4 * 8 + kh * 4);
            const f32x4 t1 = *(const f32x4*)(u + l31 * H + mt1 * 32 + r4 * 8 + kh * 4);
            acc0[4 * r4 + 0] = t0.x; acc0[4 * r4 + 1] = t0.y;
            acc0[4 * r4 + 2] = t0.z; acc0[4 * r4 + 3] = t0.w;
            acc1[4 * r4 + 0] = t1.x; acc1[4 * r4 + 1] = t1.y;
            acc1[4 * r4 + 2] = t1.z; acc1[4 * r4 + 3] = t1.w;
        }

        // B-frag source: enc row (g*32 + l31), k = s*16 + kh*8 + e
        const float* rowp = enc + ((size_t)g * 32 + l31) * H + kh * 8;

#pragma unroll
        for (int s = 0; s < 8; ++s) {
            const f32x4 xa = *(const f32x4*)(rowp + s * 16);
            const f32x4 xb = *(const f32x4*)(rowp + s * 16 + 4);
            const float xv[8] = {xa.x, xa.y, xa.z, xa.w, xb.x, xb.y, xb.z, xb.w};

            union { short8_t v8; unsigned w[4]; } bhi, blo;
#pragma unroll
            for (int p2 = 0; p2 < 4; ++p2) {
                const float x0 = xv[2 * p2], x1 = xv[2 * p2 + 1];
                const unsigned u0 = fbits(x0), u1 = fbits(x1);
                const unsigned h0 = u0 & 0xffff0000u, h1 = u1 & 0xffff0000u;
                const float r0 = x0 - bfloat(h0), r1 = x1 - bfloat(h1);
                bhi.w[p2] = (u0 >> 16) | h1;
                blo.w[p2] = (fbits(r0) >> 16) | (fbits(r1) & 0xffff0000u);
            }

            {
                const int fo0 = ((s * 4 + mt0) * 64 + lane) * 8;  // ushort idx
                const short8_t ahi = *(const short8_t*)(wlds + fo0);
                const short8_t alo = *(const short8_t*)(wlds + 16384 + fo0);
                acc0 = __builtin_amdgcn_mfma_f32_32x32x16_bf16(ahi, bhi.v8, acc0, 0, 0, 0);
                acc0 = __builtin_amdgcn_mfma_f32_32x32x16_bf16(alo, bhi.v8, acc0, 0, 0, 0);
                acc0 = __builtin_amdgcn_mfma_f32_32x32x16_bf16(ahi, blo.v8, acc0, 0, 0, 0);
            }
            {
                const int fo1 = ((s * 4 + mt1) * 64 + lane) * 8;
                const short8_t ahi = *(const short8_t*)(wlds + fo1);
                const short8_t alo = *(const short8_t*)(wlds + 16384 + fo1);
                acc1 = __builtin_amdgcn_mfma_f32_32x32x16_bf16(ahi, bhi.v8, acc1, 0, 0, 0);
                acc1 = __builtin_amdgcn_mfma_f32_32x32x16_bf16(alo, bhi.v8, acc1, 0, 0, 0);
                acc1 = __builtin_amdgcn_mfma_f32_32x32x16_bf16(ahi, blo.v8, acc1, 0, 0, 0);
            }
        }

        // --- epilogue: partial score over this wave's 64 h-rows ---
        float psum = 0.f;
#pragma unroll
        for (int r4 = 0; r4 < 4; ++r4) {
            const f32x4 v0 = *(const f32x4*)(v + mt0 * 32 + r4 * 8 + kh * 4);
            const f32x4 v1 = *(const f32x4*)(v + mt1 * 32 + r4 * 8 + kh * 4);
            psum = fmaf(fmaxf(acc0[4 * r4 + 0], 0.f), v0.x, psum);
            psum = fmaf(fmaxf(acc0[4 * r4 + 1], 0.f), v0.y, psum);
            psum = fmaf(fmaxf(acc0[4 * r4 + 2], 0.f), v0.z, psum);
            psum = fmaf(fmaxf(acc0[4 * r4 + 3], 0.f), v0.w, psum);
            psum = fmaf(fmaxf(acc1[4 * r4 + 0], 0.f), v1.x, psum);
            psum = fmaf(fmaxf(acc1[4 * r4 + 1], 0.f), v1.y, psum);
            psum = fmaf(fmaxf(acc1[4 * r4 + 2], 0.f), v1.z, psum);
            psum = fmaf(fmaxf(acc1[4 * r4 + 3], 0.f), v1.w, psum);
        }
        psum += __shfl_xor(psum, 32);   // collapse kh halves; lanes<32 hold b

        if (lane < 32) pbuf[mh][l31][gcol] = psum;   // private slot, no race
    }
    __syncthreads();

    // --- flush: thread (b, gc) sums the pair halves, coalesced store ---
    {
        const int b  = tid >> 4;
        const int gc = tid & 15;
        scores[(size_t)b * T + gbase + gc] = pbuf[0][b][gc] + pbuf[1][b][gc];
    }
}

// ---------------------------------------------------------------------------
// Kernel 3: ragged masked softmax per b, row in registers (1R + 1W).
// ---------------------------------------------------------------------------
#define SM_TPB 1024
#define SM_PER (T / SM_TPB)

__global__ __launch_bounds__(SM_TPB) void k_softmax(
    float* __restrict__ out, const int* __restrict__ len_seq)
{
    const int b    = blockIdx.x;
    const int tid  = threadIdx.x;
    const int lane = tid & 63;
    const int wid  = tid >> 6;
    const int len  = len_seq[b];
    float* s = out + (size_t)b * T;

    __shared__ float red[16];

    float val[SM_PER];
#pragma unroll
    for (int i = 0; i < SM_PER; ++i) val[i] = s[tid + i * SM_TPB];

    float m = -1e30f;
#pragma unroll
    for (int i = 0; i < SM_PER; ++i)
        if (tid + i * SM_TPB < len) m = fmaxf(m, val[i]);
#pragma unroll
    for (int off = 32; off >= 1; off >>= 1) m = fmaxf(m, __shfl_xor(m, off));
    if (lane == 0) red[wid] = m;
    __syncthreads();
    if (wid == 0) {
        float xv = (lane < 16) ? red[lane] : -1e30f;
#pragma unroll
        for (int off = 8; off >= 1; off >>= 1) xv = fmaxf(xv, __shfl_xor(xv, off));
        if (lane == 0) red[0] = xv;
    }
    __syncthreads();
    m = red[0];
    __syncthreads();

    float sum = 0.0f;
#pragma unroll
    for (int i = 0; i < SM_PER; ++i) {
        const int t = tid + i * SM_TPB;
        val[i] = (t < len) ? __expf(val[i] - m) : 0.0f;
        sum += val[i];
    }
#pragma unroll
    for (int off = 32; off >= 1; off >>= 1) sum += __shfl_xor(sum, off);
    if (lane == 0) red[wid] = sum;
    __syncthreads();
    if (wid == 0) {
        float xv = (lane < 16) ? red[lane] : 0.f;
#pragma unroll
        for (int off = 8; off >= 1; off >>= 1) xv += __shfl_xor(xv, off);
        if (lane == 0) red[0] = xv;
    }
    __syncthreads();
    const float inv = 1.0f / red[0];

#pragma unroll
    for (int i = 0; i < SM_PER; ++i) s[tid + i * SM_TPB] = val[i] * inv;
}

// ---------------------------------------------------------------------------
extern "C" void kernel_launch(void* const* d_in, const int* in_sizes, int n_in,
                              void* d_out, int out_size, void* d_ws, size_t ws_size,
                              hipStream_t stream) {
    const float* hidden = (const float*)d_in[0];
    const float* enc    = (const float*)d_in[1];
    const int*   len    = (const int*)d_in[2];
    const float* W      = (const float*)d_in[3];
    const float* bb     = (const float*)d_in[4];
    const float* v      = (const float*)d_in[5];

    float* out  = (float*)d_out;
    float* u_ws = (float*)d_ws;                                     // 16 KB
    unsigned short* wpk = (unsigned short*)((char*)d_ws + WPK_OFF); // 64 KB

    k_prep<<<40, 256, 0, stream>>>(hidden, W, bb, u_ws, wpk);
    k_scores_mfma<<<T / 16, 512, 0, stream>>>(enc, u_ws, v, wpk, out);
    k_softmax<<<B, SM_TPB, 0, stream>>>(out, len);
}

// Round 6
// 136.655 us; speedup vs baseline: 1.1596x; 1.1596x over previous
//
#include <hip/hip_runtime.h>
#include <hip/hip_bf16.h>

#define B 32
#define T 8192
#define H 128

typedef __attribute__((ext_vector_type(8)))  short short8_t;   // 8 bf16 = 4 VGPR
typedef __attribute__((ext_vector_type(16))) float f32x16;     // MFMA 32x32 acc
typedef __attribute__((ext_vector_type(4)))  float f32x4;

static __device__ __forceinline__ unsigned fbits(float x) { return __builtin_bit_cast(unsigned, x); }
static __device__ __forceinline__ float bfloat(unsigned u) { return __builtin_bit_cast(float, u); }

// ws layout: [0,16K) u fp32 ; [16K,48K) W2 hi-frags bf16 ; [48K,80K) W2 lo-frags
#define WPK_OFF 16384

// ---------------------------------------------------------------------------
// Kernel 1 (merged prep): blocks 0..31 -> u[b][h]; blocks 32..39 -> pack W2.
//   u[b][h] = b_attn[h] + dot(W1[h,:], hidden[b,:])          (fp32 exact)
//   wpk: A-frags for v_mfma_f32_32x32x16_bf16, hi plane then lo plane.
//   A-frag: lane l supplies A[m*32 + (l&31)][s*16 + (l>>5)*8 + e], e=0..7;
//   buffer index frag[s][m][lane][e].
// ---------------------------------------------------------------------------
__global__ void k_prep(const float* __restrict__ hidden,
                       const float* __restrict__ W_attn,
                       const float* __restrict__ b_attn,
                       float* __restrict__ u,
                       unsigned short* __restrict__ wpk) {
    const int tid = threadIdx.x;
    if (blockIdx.x < 32) {
        const int b = blockIdx.x;
        __shared__ float hrow[H];
        if (tid < H) hrow[tid] = hidden[b * H + tid];
        __syncthreads();
        if (tid < H) {
            const float* w = W_attn + (size_t)tid * (2 * H);
            float acc = b_attn[tid];
#pragma unroll
            for (int k = 0; k < H; ++k) acc = fmaf(w[k], hrow[k], acc);
            u[b * H + tid] = acc;
        }
    } else {
        const int idx  = (blockIdx.x - 32) * 256 + tid;   // 0..2047
        const int s    = idx >> 8;
        const int m    = (idx >> 6) & 3;
        const int lane = idx & 63;
        const int h    = m * 32 + (lane & 31);
        const int k0   = s * 16 + (lane >> 5) * 8;
        const float* src = W_attn + (size_t)h * (2 * H) + H + k0;
        const int base = ((s * 4 + m) * 64 + lane) * 8;
#pragma unroll
        for (int e = 0; e < 8; ++e) {
            const float x = src[e];
            const unsigned ux = fbits(x);
            const unsigned hb = ux & 0xffff0000u;         // truncated bf16 hi
            const float r = x - bfloat(hb);               // exact remainder
            wpk[base + e]         = (unsigned short)(ux >> 16);
            wpk[16384 + base + e] = (unsigned short)(fbits(r) >> 16);
        }
    }
}

// ---------------------------------------------------------------------------
// Kernel 2: scores via MFMA, wave-paired (mh = h-half).
// ROUND-4 loop structure (gi<2, grid 1024, 8 t-groups/block) — proven
// spill-free — with ONE change: the per-gi pair-combine (2 barriers/gi +
// scattered dword stores) is replaced by private pbuf slots, a single
// barrier after the loop, and a coalesced flush.
// pbuf padded to 9 floats/row: write bank = (9*l31 + gcol) % 32, 9 odd ->
// bijection over l31 -> conflict-free.
// ---------------------------------------------------------------------------
__global__ __launch_bounds__(512, 4) void k_scores_mfma(
    const float* __restrict__ enc,                 // [T*B][H]
    const float* __restrict__ u,                   // [B][H]
    const float* __restrict__ v,                   // [H]
    const unsigned short* __restrict__ wpk,        // 64 KB frag-ordered hi|lo
    float* __restrict__ scores)                    // [B][T]
{
    __shared__ unsigned short wlds[32768];         // 64 KB
    __shared__ float pbuf[2][32][9];               // [mh][b][gcol] padded

    const int tid  = threadIdx.x;
    const int lane = tid & 63;
    const int wid  = tid >> 6;      // 0..7
    const int pair = wid >> 1;      // 0..3 : t-group owner
    const int mh   = wid & 1;       // h-half: tiles {2mh, 2mh+1}
    const int l31  = lane & 31;
    const int kh   = lane >> 5;
    const int mt0  = mh * 2;
    const int mt1  = mh * 2 + 1;

    // one-time stage of packed W2 frags
    {
        const f32x4* src = (const f32x4*)wpk;
        f32x4* dst = (f32x4*)wlds;
#pragma unroll
        for (int i = 0; i < 8; ++i) dst[tid + i * 512] = src[tid + i * 512];
    }
    __syncthreads();

    const int gbase = blockIdx.x * 8;

    for (int gi = 0; gi < 2; ++gi) {
        const int gcol = pair * 2 + gi;
        const int g    = gbase + gcol;             // t index

        // --- acc init = u fragment (C/D row = j + 8*r4 + 4*kh, col = b = l31)
        f32x16 acc0, acc1;
#pragma unroll
        for (int r4 = 0; r4 < 4; ++r4) {
            const f32x4 t0 = *(const f32x4*)(u + l31 * H + mt0 * 32 + r4 * 8 + kh * 4);
            const f32x4 t1 = *(const f32x4*)(u + l31 * H + mt1 * 32 + r4 * 8 + kh * 4);
            acc0[4 * r4 + 0] = t0.x; acc0[4 * r4 + 1] = t0.y;
            acc0[4 * r4 + 2] = t0.z; acc0[4 * r4 + 3] = t0.w;
            acc1[4 * r4 + 0] = t1.x; acc1[4 * r4 + 1] = t1.y;
            acc1[4 * r4 + 2] = t1.z; acc1[4 * r4 + 3] = t1.w;
        }

        // B-frag source: enc row (g*32 + l31), k = s*16 + kh*8 + e
        const float* rowp = enc + ((size_t)g * 32 + l31) * H + kh * 8;

#pragma unroll
        for (int s = 0; s < 8; ++s) {
            const f32x4 xa = *(const f32x4*)(rowp + s * 16);
            const f32x4 xb = *(const f32x4*)(rowp + s * 16 + 4);
            const float xv[8] = {xa.x, xa.y, xa.z, xa.w, xb.x, xb.y, xb.z, xb.w};

            union { short8_t v8; unsigned w[4]; } bhi, blo;
#pragma unroll
            for (int p2 = 0; p2 < 4; ++p2) {
                const float x0 = xv[2 * p2], x1 = xv[2 * p2 + 1];
                const unsigned u0 = fbits(x0), u1 = fbits(x1);
                const unsigned h0 = u0 & 0xffff0000u, h1 = u1 & 0xffff0000u;
                const float r0 = x0 - bfloat(h0), r1 = x1 - bfloat(h1);
                bhi.w[p2] = (u0 >> 16) | h1;
                blo.w[p2] = (fbits(r0) >> 16) | (fbits(r1) & 0xffff0000u);
            }

            {
                const int fo0 = ((s * 4 + mt0) * 64 + lane) * 8;  // ushort idx
                const short8_t ahi = *(const short8_t*)(wlds + fo0);
                const short8_t alo = *(const short8_t*)(wlds + 16384 + fo0);
                acc0 = __builtin_amdgcn_mfma_f32_32x32x16_bf16(ahi, bhi.v8, acc0, 0, 0, 0);
                acc0 = __builtin_amdgcn_mfma_f32_32x32x16_bf16(alo, bhi.v8, acc0, 0, 0, 0);
                acc0 = __builtin_amdgcn_mfma_f32_32x32x16_bf16(ahi, blo.v8, acc0, 0, 0, 0);
            }
            {
                const int fo1 = ((s * 4 + mt1) * 64 + lane) * 8;
                const short8_t ahi = *(const short8_t*)(wlds + fo1);
                const short8_t alo = *(const short8_t*)(wlds + 16384 + fo1);
                acc1 = __builtin_amdgcn_mfma_f32_32x32x16_bf16(ahi, bhi.v8, acc1, 0, 0, 0);
                acc1 = __builtin_amdgcn_mfma_f32_32x32x16_bf16(alo, bhi.v8, acc1, 0, 0, 0);
                acc1 = __builtin_amdgcn_mfma_f32_32x32x16_bf16(ahi, blo.v8, acc1, 0, 0, 0);
            }
        }

        // --- epilogue: partial score over this wave's 64 h-rows ---
        float psum = 0.f;
#pragma unroll
        for (int r4 = 0; r4 < 4; ++r4) {
            const f32x4 v0 = *(const f32x4*)(v + mt0 * 32 + r4 * 8 + kh * 4);
            const f32x4 v1 = *(const f32x4*)(v + mt1 * 32 + r4 * 8 + kh * 4);
            psum = fmaf(fmaxf(acc0[4 * r4 + 0], 0.f), v0.x, psum);
            psum = fmaf(fmaxf(acc0[4 * r4 + 1], 0.f), v0.y, psum);
            psum = fmaf(fmaxf(acc0[4 * r4 + 2], 0.f), v0.z, psum);
            psum = fmaf(fmaxf(acc0[4 * r4 + 3], 0.f), v0.w, psum);
            psum = fmaf(fmaxf(acc1[4 * r4 + 0], 0.f), v1.x, psum);
            psum = fmaf(fmaxf(acc1[4 * r4 + 1], 0.f), v1.y, psum);
            psum = fmaf(fmaxf(acc1[4 * r4 + 2], 0.f), v1.z, psum);
            psum = fmaf(fmaxf(acc1[4 * r4 + 3], 0.f), v1.w, psum);
        }
        psum += __shfl_xor(psum, 32);   // collapse kh halves; lanes<32 hold b

        if (lane < 32) pbuf[mh][l31][gcol] = psum;   // private slot, no race
    }
    __syncthreads();

    // --- flush: thread (b, gc) sums the pair halves, coalesced store ---
    if (tid < 256) {
        const int b  = tid >> 3;
        const int gc = tid & 7;
        scores[(size_t)b * T + gbase + gc] = pbuf[0][b][gc] + pbuf[1][b][gc];
    }
}

// ---------------------------------------------------------------------------
// Kernel 3: ragged masked softmax per b, row in registers (1R + 1W).
// ---------------------------------------------------------------------------
#define SM_TPB 1024
#define SM_PER (T / SM_TPB)

__global__ __launch_bounds__(SM_TPB) void k_softmax(
    float* __restrict__ out, const int* __restrict__ len_seq)
{
    const int b    = blockIdx.x;
    const int tid  = threadIdx.x;
    const int lane = tid & 63;
    const int wid  = tid >> 6;
    const int len  = len_seq[b];
    float* s = out + (size_t)b * T;

    __shared__ float red[16];

    float val[SM_PER];
#pragma unroll
    for (int i = 0; i < SM_PER; ++i) val[i] = s[tid + i * SM_TPB];

    float m = -1e30f;
#pragma unroll
    for (int i = 0; i < SM_PER; ++i)
        if (tid + i * SM_TPB < len) m = fmaxf(m, val[i]);
#pragma unroll
    for (int off = 32; off >= 1; off >>= 1) m = fmaxf(m, __shfl_xor(m, off));
    if (lane == 0) red[wid] = m;
    __syncthreads();
    if (wid == 0) {
        float xv = (lane < 16) ? red[lane] : -1e30f;
#pragma unroll
        for (int off = 8; off >= 1; off >>= 1) xv = fmaxf(xv, __shfl_xor(xv, off));
        if (lane == 0) red[0] = xv;
    }
    __syncthreads();
    m = red[0];
    __syncthreads();

    float sum = 0.0f;
#pragma unroll
    for (int i = 0; i < SM_PER; ++i) {
        const int t = tid + i * SM_TPB;
        val[i] = (t < len) ? __expf(val[i] - m) : 0.0f;
        sum += val[i];
    }
#pragma unroll
    for (int off = 32; off >= 1; off >>= 1) sum += __shfl_xor(sum, off);
    if (lane == 0) red[wid] = sum;
    __syncthreads();
    if (wid == 0) {
        float xv = (lane < 16) ? red[lane] : 0.f;
#pragma unroll
        for (int off = 8; off >= 1; off >>= 1) xv += __shfl_xor(xv, off);
        if (lane == 0) red[0] = xv;
    }
    __syncthreads();
    const float inv = 1.0f / red[0];

#pragma unroll
    for (int i = 0; i < SM_PER; ++i) s[tid + i * SM_TPB] = val[i] * inv;
}

// ---------------------------------------------------------------------------
extern "C" void kernel_launch(void* const* d_in, const int* in_sizes, int n_in,
                              void* d_out, int out_size, void* d_ws, size_t ws_size,
                              hipStream_t stream) {
    const float* hidden = (const float*)d_in[0];
    const float* enc    = (const float*)d_in[1];
    const int*   len    = (const int*)d_in[2];
    const float* W      = (const float*)d_in[3];
    const float* bb     = (const float*)d_in[4];
    const float* v      = (const float*)d_in[5];

    float* out  = (float*)d_out;
    float* u_ws = (float*)d_ws;                                     // 16 KB
    unsigned short* wpk = (unsigned short*)((char*)d_ws + WPK_OFF); // 64 KB

    k_prep<<<40, 256, 0, stream>>>(hidden, W, bb, u_ws, wpk);
    k_scores_mfma<<<T / 8, 512, 0, stream>>>(enc, u_ws, v, wpk, out);
    k_softmax<<<B, SM_TPB, 0, stream>>>(out, len);
}

// Round 7
// 57.728 us; speedup vs baseline: 2.7450x; 2.3672x over previous
//
#include <hip/hip_runtime.h>
#include <hip/hip_bf16.h>

#define B 32
#define T 8192
#define H 128

typedef __attribute__((ext_vector_type(8)))  short short8_t;   // 8 bf16 = 4 VGPR
typedef __attribute__((ext_vector_type(16))) float f32x16;     // MFMA 32x32 acc
typedef __attribute__((ext_vector_type(4)))  float f32x4;

static __device__ __forceinline__ unsigned fbits(float x) { return __builtin_bit_cast(unsigned, x); }
static __device__ __forceinline__ float bfloat(unsigned u) { return __builtin_bit_cast(float, u); }

// ws layout: [0,16K) u fp32 ; [16K,48K) W2 hi-frags bf16 ; [48K,80K) W2 lo-frags
#define WPK_OFF 16384

// ---------------------------------------------------------------------------
// Kernel 1 (merged prep): blocks 0..31 -> u[b][h]; blocks 32..39 -> pack W2.
//   u[b][h] = b_attn[h] + dot(W1[h,:], hidden[b,:])          (fp32 exact)
//   wpk: A-frags for v_mfma_f32_32x32x16_bf16, hi plane then lo plane.
//   A-frag: lane l supplies A[m*32 + (l&31)][s*16 + (l>>5)*8 + e], e=0..7;
//   buffer index frag[s][m][lane][e].
// ---------------------------------------------------------------------------
__global__ void k_prep(const float* __restrict__ hidden,
                       const float* __restrict__ W_attn,
                       const float* __restrict__ b_attn,
                       float* __restrict__ u,
                       unsigned short* __restrict__ wpk) {
    const int tid = threadIdx.x;
    if (blockIdx.x < 32) {
        const int b = blockIdx.x;
        __shared__ float hrow[H];
        if (tid < H) hrow[tid] = hidden[b * H + tid];
        __syncthreads();
        if (tid < H) {
            const float* w = W_attn + (size_t)tid * (2 * H);
            float acc = b_attn[tid];
#pragma unroll
            for (int k = 0; k < H; ++k) acc = fmaf(w[k], hrow[k], acc);
            u[b * H + tid] = acc;
        }
    } else {
        const int idx  = (blockIdx.x - 32) * 256 + tid;   // 0..2047
        const int s    = idx >> 8;
        const int m    = (idx >> 6) & 3;
        const int lane = idx & 63;
        const int h    = m * 32 + (lane & 31);
        const int k0   = s * 16 + (lane >> 5) * 8;
        const float* src = W_attn + (size_t)h * (2 * H) + H + k0;
        const int base = ((s * 4 + m) * 64 + lane) * 8;
#pragma unroll
        for (int e = 0; e < 8; ++e) {
            const float x = src[e];
            const unsigned ux = fbits(x);
            const unsigned hb = ux & 0xffff0000u;         // truncated bf16 hi
            const float r = x - bfloat(hb);               // exact remainder
            wpk[base + e]         = (unsigned short)(ux >> 16);
            wpk[16384 + base + e] = (unsigned short)(fbits(r) >> 16);
        }
    }
}

// ---------------------------------------------------------------------------
// Kernel 2: scores via MFMA, wave-paired — EXACT round-4 body (proven 59.9 µs,
// no spill). The two in-loop __syncthreads() double as scheduling fences:
// every barrier-free variant of this loop (rounds 3/5/6) spilled ~130-360 MB
// of scratch under the 128-reg cap. Do not remove them without also raising
// the register budget.
// Wave pair (2p, 2p+1) shares one t-group g; wave mh computes h-tiles
// {2mh, 2mh+1}: acc = 2 x f32x16 = 32 regs. C-init = u fragment; epilogue
// relu*v reduces in-lane; pair partials combine through 32-float LDS slots.
// 1024 blocks x 512 thr; 8 t-values per block.
// ---------------------------------------------------------------------------
__global__ __launch_bounds__(512, 4) void k_scores_mfma(
    const float* __restrict__ enc,                 // [T*B][H]
    const float* __restrict__ u,                   // [B][H]
    const float* __restrict__ v,                   // [H]
    const unsigned short* __restrict__ wpk,        // 64 KB frag-ordered hi|lo
    float* __restrict__ scores)                    // [B][T]
{
    __shared__ unsigned short wlds[32768];         // 64 KB
    __shared__ float pairbuf[4][32];

    const int tid  = threadIdx.x;
    const int lane = tid & 63;
    const int wid  = tid >> 6;      // 0..7
    const int pair = wid >> 1;      // 0..3 : t-group owner
    const int mh   = wid & 1;       // h-half: tiles {2mh, 2mh+1}
    const int l31  = lane & 31;
    const int kh   = lane >> 5;
    const int mt0  = mh * 2;
    const int mt1  = mh * 2 + 1;

    // one-time stage of packed W2 frags
    {
        const f32x4* src = (const f32x4*)wpk;
        f32x4* dst = (f32x4*)wlds;
#pragma unroll
        for (int i = 0; i < 8; ++i) dst[tid + i * 512] = src[tid + i * 512];
    }
    __syncthreads();

    const int gbase = blockIdx.x * 8 + pair * 2;

    for (int gi = 0; gi < 2; ++gi) {
        const int g = gbase + gi;                  // t index

        // --- acc init = u fragment (C/D row = j + 8*r4 + 4*kh, col = b = l31)
        f32x16 acc0, acc1;
#pragma unroll
        for (int r4 = 0; r4 < 4; ++r4) {
            const f32x4 t0 = *(const f32x4*)(u + l31 * H + mt0 * 32 + r4 * 8 + kh * 4);
            const f32x4 t1 = *(const f32x4*)(u + l31 * H + mt1 * 32 + r4 * 8 + kh * 4);
            acc0[4 * r4 + 0] = t0.x; acc0[4 * r4 + 1] = t0.y;
            acc0[4 * r4 + 2] = t0.z; acc0[4 * r4 + 3] = t0.w;
            acc1[4 * r4 + 0] = t1.x; acc1[4 * r4 + 1] = t1.y;
            acc1[4 * r4 + 2] = t1.z; acc1[4 * r4 + 3] = t1.w;
        }

        // B-frag source: enc row (g*32 + l31), k = s*16 + kh*8 + e
        const float* rowp = enc + ((size_t)g * 32 + l31) * H + kh * 8;

#pragma unroll
        for (int s = 0; s < 8; ++s) {
            const f32x4 xa = *(const f32x4*)(rowp + s * 16);
            const f32x4 xb = *(const f32x4*)(rowp + s * 16 + 4);
            const float xv[8] = {xa.x, xa.y, xa.z, xa.w, xb.x, xb.y, xb.z, xb.w};

            union { short8_t v8; unsigned w[4]; } bhi, blo;
#pragma unroll
            for (int p2 = 0; p2 < 4; ++p2) {
                const float x0 = xv[2 * p2], x1 = xv[2 * p2 + 1];
                const unsigned u0 = fbits(x0), u1 = fbits(x1);
                const unsigned h0 = u0 & 0xffff0000u, h1 = u1 & 0xffff0000u;
                const float r0 = x0 - bfloat(h0), r1 = x1 - bfloat(h1);
                bhi.w[p2] = (u0 >> 16) | h1;
                blo.w[p2] = (fbits(r0) >> 16) | (fbits(r1) & 0xffff0000u);
            }

            {
                const int fo0 = ((s * 4 + mt0) * 64 + lane) * 8;  // ushort idx
                const short8_t ahi = *(const short8_t*)(wlds + fo0);
                const short8_t alo = *(const short8_t*)(wlds + 16384 + fo0);
                acc0 = __builtin_amdgcn_mfma_f32_32x32x16_bf16(ahi, bhi.v8, acc0, 0, 0, 0);
                acc0 = __builtin_amdgcn_mfma_f32_32x32x16_bf16(alo, bhi.v8, acc0, 0, 0, 0);
                acc0 = __builtin_amdgcn_mfma_f32_32x32x16_bf16(ahi, blo.v8, acc0, 0, 0, 0);
            }
            {
                const int fo1 = ((s * 4 + mt1) * 64 + lane) * 8;
                const short8_t ahi = *(const short8_t*)(wlds + fo1);
                const short8_t alo = *(const short8_t*)(wlds + 16384 + fo1);
                acc1 = __builtin_amdgcn_mfma_f32_32x32x16_bf16(ahi, bhi.v8, acc1, 0, 0, 0);
                acc1 = __builtin_amdgcn_mfma_f32_32x32x16_bf16(alo, bhi.v8, acc1, 0, 0, 0);
                acc1 = __builtin_amdgcn_mfma_f32_32x32x16_bf16(ahi, blo.v8, acc1, 0, 0, 0);
            }
        }

        // --- epilogue: partial score over this wave's 64 h-rows ---
        float psum = 0.f;
#pragma unroll
        for (int r4 = 0; r4 < 4; ++r4) {
            const f32x4 v0 = *(const f32x4*)(v + mt0 * 32 + r4 * 8 + kh * 4);
            const f32x4 v1 = *(const f32x4*)(v + mt1 * 32 + r4 * 8 + kh * 4);
            psum = fmaf(fmaxf(acc0[4 * r4 + 0], 0.f), v0.x, psum);
            psum = fmaf(fmaxf(acc0[4 * r4 + 1], 0.f), v0.y, psum);
            psum = fmaf(fmaxf(acc0[4 * r4 + 2], 0.f), v0.z, psum);
            psum = fmaf(fmaxf(acc0[4 * r4 + 3], 0.f), v0.w, psum);
            psum = fmaf(fmaxf(acc1[4 * r4 + 0], 0.f), v1.x, psum);
            psum = fmaf(fmaxf(acc1[4 * r4 + 1], 0.f), v1.y, psum);
            psum = fmaf(fmaxf(acc1[4 * r4 + 2], 0.f), v1.z, psum);
            psum = fmaf(fmaxf(acc1[4 * r4 + 3], 0.f), v1.w, psum);
        }
        psum += __shfl_xor(psum, 32);   // collapse kh halves; lanes<32 hold b

        // --- pair combine via LDS (in-loop barriers = scheduling fences) ---
        if (mh == 0 && lane < 32) pairbuf[pair][l31] = psum;
        __syncthreads();
        if (mh == 1 && lane < 32)
            scores[(size_t)l31 * T + g] = psum + pairbuf[pair][l31];
        __syncthreads();
    }
}

// ---------------------------------------------------------------------------
// Kernel 3: ragged masked softmax per b, row in registers (1R + 1W).
// ---------------------------------------------------------------------------
#define SM_TPB 1024
#define SM_PER (T / SM_TPB)

__global__ __launch_bounds__(SM_TPB) void k_softmax(
    float* __restrict__ out, const int* __restrict__ len_seq)
{
    const int b    = blockIdx.x;
    const int tid  = threadIdx.x;
    const int lane = tid & 63;
    const int wid  = tid >> 6;
    const int len  = len_seq[b];
    float* s = out + (size_t)b * T;

    __shared__ float red[16];

    float val[SM_PER];
#pragma unroll
    for (int i = 0; i < SM_PER; ++i) val[i] = s[tid + i * SM_TPB];

    float m = -1e30f;
#pragma unroll
    for (int i = 0; i < SM_PER; ++i)
        if (tid + i * SM_TPB < len) m = fmaxf(m, val[i]);
#pragma unroll
    for (int off = 32; off >= 1; off >>= 1) m = fmaxf(m, __shfl_xor(m, off));
    if (lane == 0) red[wid] = m;
    __syncthreads();
    if (wid == 0) {
        float xv = (lane < 16) ? red[lane] : -1e30f;
#pragma unroll
        for (int off = 8; off >= 1; off >>= 1) xv = fmaxf(xv, __shfl_xor(xv, off));
        if (lane == 0) red[0] = xv;
    }
    __syncthreads();
    m = red[0];
    __syncthreads();

    float sum = 0.0f;
#pragma unroll
    for (int i = 0; i < SM_PER; ++i) {
        const int t = tid + i * SM_TPB;
        val[i] = (t < len) ? __expf(val[i] - m) : 0.0f;
        sum += val[i];
    }
#pragma unroll
    for (int off = 32; off >= 1; off >>= 1) sum += __shfl_xor(sum, off);
    if (lane == 0) red[wid] = sum;
    __syncthreads();
    if (wid == 0) {
        float xv = (lane < 16) ? red[lane] : 0.f;
#pragma unroll
        for (int off = 8; off >= 1; off >>= 1) xv += __shfl_xor(xv, off);
        if (lane == 0) red[0] = xv;
    }
    __syncthreads();
    const float inv = 1.0f / red[0];

#pragma unroll
    for (int i = 0; i < SM_PER; ++i) s[tid + i * SM_TPB] = val[i] * inv;
}

// ---------------------------------------------------------------------------
extern "C" void kernel_launch(void* const* d_in, const int* in_sizes, int n_in,
                              void* d_out, int out_size, void* d_ws, size_t ws_size,
                              hipStream_t stream) {
    const float* hidden = (const float*)d_in[0];
    const float* enc    = (const float*)d_in[1];
    const int*   len    = (const int*)d_in[2];
    const float* W      = (const float*)d_in[3];
    const float* bb     = (const float*)d_in[4];
    const float* v      = (const float*)d_in[5];

    float* out  = (float*)d_out;
    float* u_ws = (float*)d_ws;                                     // 16 KB
    unsigned short* wpk = (unsigned short*)((char*)d_ws + WPK_OFF); // 64 KB

    k_prep<<<40, 256, 0, stream>>>(hidden, W, bb, u_ws, wpk);
    k_scores_mfma<<<T / 8, 512, 0, stream>>>(enc, u_ws, v, wpk, out);
    k_softmax<<<B, SM_TPB, 0, stream>>>(out, len);
}